// Round 1
// 12702.256 us; speedup vs baseline: 1.1164x; 1.1164x over previous
//
#include <hip/hip_runtime.h>

// GRU (reverse scan), B=128 T=1024 H=256. fp32 in/out.
// Persistent cooperative kernel, 32 WGs = 2 batch-halves x 16 hidden slices.
// Compensated bf16 MFMA (hi*hi + lo*hi + hi*lo), weights hi/lo in LDS (101 KB).
//
// ROUND CHANGE: replace cg::grid.sync() (13.9 us/step: device-scope L2
// writeback+invalidate across 8 XCDs) with two independent 16-WG flag
// barriers (one per batch-half; that's the true dependency group) and
// agent-scope (sc1, L2-bypassing) atomics for the h exchange. x-side GEMM
// moved before the wait; hold carried in registers; h stored pre-split as
// packed (lo16|hi16); next-step x register-prefetched; out via nt stores.

#define TT 1024
#define BB 128
#define HH 256

typedef unsigned short u16;
typedef unsigned int   u32;
typedef __attribute__((ext_vector_type(8))) short  bf16x8;
typedef __attribute__((ext_vector_type(4))) float  f32x4;

static constexpr int NWG_B  = 2;
static constexpr int NWG_H  = 16;
static constexpr int NWG    = NWG_B * NWG_H;   // 32 workgroups
static constexpr int BS     = BB / NWG_B;      // 64 batch rows per WG
static constexpr int HS     = HH / NWG_H;      // 16 hidden cols per WG
static constexpr int WPITCH = HH + 8;          // LDS row pitch (16B-aligned, conflict pad)
static constexpr int LO_OFF = 96 * WPITCH;     // lo-plane offset in LDS elements
static constexpr int LDS_BYTES = 192 * WPITCH * 2;  // 101376 B
static constexpr int CTR_OFF = 2 * BB * HH;    // u32 index of barrier counters in ws

__device__ __forceinline__ float b2f(u16 u) {
  union { unsigned i; float f; } v; v.i = ((unsigned)u) << 16; return v.f;
}
__device__ __forceinline__ u16 f2b(float f) {   // RNE fp32 -> bf16
  union { float f; unsigned i; } v; v.f = f;
  return (u16)((v.i + 0x7fffu + ((v.i >> 16) & 1u)) >> 16);
}
__device__ __forceinline__ float sigm(float x) { return 1.0f / (1.0f + __expf(-x)); }
__device__ __forceinline__ float tanh_fast(float x) {
  float a = fabsf(x);
  float e = __expf(-2.0f * a);
  float t = (1.0f - e) / (1.0f + e);
  return copysignf(t, x);
}
// split two f32x4 registers into hi/lo bf16 fragments
__device__ __forceinline__ void split8r(f32x4 a, f32x4 b, bf16x8& hi, bf16x8& lo) {
  union { bf16x8 v; u16 e[8]; } uh, ul;
#pragma unroll
  for (int j = 0; j < 4; ++j) {
    const u16 h0 = f2b(a[j]); uh.e[j]     = h0; ul.e[j]     = f2b(a[j] - b2f(h0));
    const u16 h1 = f2b(b[j]); uh.e[4 + j] = h1; ul.e[4 + j] = f2b(b[j] - b2f(h1));
  }
  hi = uh.v; lo = ul.v;
}
// unpack 8 packed (lo16<<16|hi16) words into hi/lo bf16 fragments
__device__ __forceinline__ void unpack8(const u32* w, bf16x8& hi, bf16x8& lo) {
  union { bf16x8 v; u32 u[4]; } fh, fl;
#pragma unroll
  for (int j = 0; j < 4; ++j) {
    const u32 a = w[2 * j], b = w[2 * j + 1];
    fh.u[j] = (a & 0xffffu) | (b << 16);          // hi halves  -> v_perm
    fl.u[j] = (a >> 16) | (b & 0xffff0000u);      // lo halves
  }
  hi = fh.v; lo = fl.v;
}

// prefetch one step's x tile (16 f32x4 per lane) into register buffer XB
#define XLOAD(XB, TSV) {                                                     \
  const float* xp_ = xrowbase + (size_t)(TSV) * HH;                          \
  _Pragma("unroll") for (int kf_ = 0; kf_ < 8; ++kf_) {                      \
    XB[2 * kf_]     = *(const f32x4*)(xp_ + kf_ * 32);                       \
    XB[2 * kf_ + 1] = *(const f32x4*)(xp_ + kf_ * 32 + 4);                   \
  } }

#define GRU_STEP(S, XC, XN) {                                                \
  const int s_  = (S);                                                       \
  const int ts_ = TT - 1 - s_;                                               \
  const int rbuf_ = s_ & 1;                                                  \
  /* prefetch next step's x (independent of everything below) */             \
  { int tsn_ = ts_ - 1; if (tsn_ < 0) tsn_ = 0; XLOAD(XN, tsn_); }           \
  /* ---- x-part MFMAs: gi = x @ W_ih^T (no h dependence) ---- */            \
  f32x4 air = {0,0,0,0}, aiz = {0,0,0,0}, ain = {0,0,0,0};                   \
  f32x4 ahr = {0,0,0,0}, ahz = {0,0,0,0}, ahn = {0,0,0,0};                   \
  _Pragma("unroll") for (int kf = 0; kf < 8; ++kf) {                         \
    bf16x8 xhi, xlo; split8r(XC[2 * kf], XC[2 * kf + 1], xhi, xlo);          \
    const int ko = kf * 32;                                                  \
    bf16x8 wr  = *(const bf16x8*)&lds_w[woff[0][0] + ko];                    \
    bf16x8 wz  = *(const bf16x8*)&lds_w[woff[0][1] + ko];                    \
    bf16x8 wn  = *(const bf16x8*)&lds_w[woff[0][2] + ko];                    \
    air = __builtin_amdgcn_mfma_f32_16x16x32_bf16(xhi, wr, air, 0, 0, 0);    \
    aiz = __builtin_amdgcn_mfma_f32_16x16x32_bf16(xhi, wz, aiz, 0, 0, 0);    \
    ain = __builtin_amdgcn_mfma_f32_16x16x32_bf16(xhi, wn, ain, 0, 0, 0);    \
    air = __builtin_amdgcn_mfma_f32_16x16x32_bf16(xlo, wr, air, 0, 0, 0);    \
    aiz = __builtin_amdgcn_mfma_f32_16x16x32_bf16(xlo, wz, aiz, 0, 0, 0);    \
    ain = __builtin_amdgcn_mfma_f32_16x16x32_bf16(xlo, wn, ain, 0, 0, 0);    \
    bf16x8 wrl = *(const bf16x8*)&lds_w[LO_OFF + woff[0][0] + ko];           \
    bf16x8 wzl = *(const bf16x8*)&lds_w[LO_OFF + woff[0][1] + ko];           \
    bf16x8 wnl = *(const bf16x8*)&lds_w[LO_OFF + woff[0][2] + ko];           \
    air = __builtin_amdgcn_mfma_f32_16x16x32_bf16(xhi, wrl, air, 0, 0, 0);   \
    aiz = __builtin_amdgcn_mfma_f32_16x16x32_bf16(xhi, wzl, aiz, 0, 0, 0);   \
    ain = __builtin_amdgcn_mfma_f32_16x16x32_bf16(xhi, wnl, ain, 0, 0, 0);   \
  }                                                                          \
  /* ---- wait: group mates finished step s-1 (h[rbuf_] fully written) */    \
  if (s_ > 0) {                                                              \
    if (tid == 0) {                                                          \
      const u32 tgt_ = (u32)(NWG_H * s_);                                    \
      while (__hip_atomic_load(ctrp, __ATOMIC_RELAXED,                       \
                               __HIP_MEMORY_SCOPE_AGENT) < tgt_)             \
        __builtin_amdgcn_s_sleep(1);                                         \
    }                                                                        \
    __syncthreads();                                                         \
  }                                                                          \
  /* ---- h loads: packed hi/lo via agent-scope (L2-bypassing) atomics */    \
  {                                                                          \
    const u32* hp_ = hb0 + (size_t)rbuf_ * BB * HH + (size_t)abrow * HH      \
                     + quad * 8;                                             \
    u32 hr32[64];                                                            \
    _Pragma("unroll") for (int kf = 0; kf < 8; ++kf)                         \
      _Pragma("unroll") for (int j = 0; j < 8; ++j)                          \
        hr32[kf * 8 + j] = __hip_atomic_load(hp_ + kf * 32 + j,              \
                             __ATOMIC_RELAXED, __HIP_MEMORY_SCOPE_AGENT);    \
    _Pragma("unroll") for (int kf = 0; kf < 8; ++kf) {                       \
      bf16x8 hhi, hlo; unpack8(&hr32[kf * 8], hhi, hlo);                     \
      const int ko = kf * 32;                                                \
      bf16x8 vr  = *(const bf16x8*)&lds_w[woff[1][0] + ko];                  \
      bf16x8 vz  = *(const bf16x8*)&lds_w[woff[1][1] + ko];                  \
      bf16x8 vn  = *(const bf16x8*)&lds_w[woff[1][2] + ko];                  \
      ahr = __builtin_amdgcn_mfma_f32_16x16x32_bf16(hhi, vr, ahr, 0, 0, 0);  \
      ahz = __builtin_amdgcn_mfma_f32_16x16x32_bf16(hhi, vz, ahz, 0, 0, 0);  \
      ahn = __builtin_amdgcn_mfma_f32_16x16x32_bf16(hhi, vn, ahn, 0, 0, 0);  \
      ahr = __builtin_amdgcn_mfma_f32_16x16x32_bf16(hlo, vr, ahr, 0, 0, 0);  \
      ahz = __builtin_amdgcn_mfma_f32_16x16x32_bf16(hlo, vz, ahz, 0, 0, 0);  \
      ahn = __builtin_amdgcn_mfma_f32_16x16x32_bf16(hlo, vn, ahn, 0, 0, 0);  \
      bf16x8 vrl = *(const bf16x8*)&lds_w[LO_OFF + woff[1][0] + ko];         \
      bf16x8 vzl = *(const bf16x8*)&lds_w[LO_OFF + woff[1][1] + ko];         \
      bf16x8 vnl = *(const bf16x8*)&lds_w[LO_OFF + woff[1][2] + ko];         \
      ahr = __builtin_amdgcn_mfma_f32_16x16x32_bf16(hhi, vrl, ahr, 0, 0, 0); \
      ahz = __builtin_amdgcn_mfma_f32_16x16x32_bf16(hhi, vzl, ahz, 0, 0, 0); \
      ahn = __builtin_amdgcn_mfma_f32_16x16x32_bf16(hhi, vnl, ahn, 0, 0, 0); \
    }                                                                        \
  }                                                                          \
  /* ---- gates + state update (hold carried in registers) ---- */           \
  {                                                                          \
    u32* hw_ = hb0 + (size_t)(rbuf_ ^ 1) * BB * HH;                          \
    _Pragma("unroll") for (int i = 0; i < 4; ++i) {                          \
      const int rb = row0 + quad * 4 + i;                                    \
      const float rg = sigm(air[i] + ahr[i] + bsum_r);                       \
      const float zg = sigm(aiz[i] + ahz[i] + bsum_z);                       \
      const float ng = tanh_fast(ain[i] + bi_n + rg * (ahn[i] + bh_n));      \
      const float hnew = (1.0f - zg) * ng + zg * hprev[i];                   \
      hprev[i] = hnew;                                                       \
      __builtin_nontemporal_store(hnew,                                      \
          &out[((size_t)rb * TT + ts_) * HH + cd]);                          \
      const u16 ph_ = f2b(hnew);                                             \
      const u16 pl_ = f2b(hnew - b2f(ph_));                                  \
      __hip_atomic_store(&hw_[(size_t)rb * HH + cd],                         \
                         ((u32)pl_ << 16) | (u32)ph_,                        \
                         __ATOMIC_RELAXED, __HIP_MEMORY_SCOPE_AGENT);        \
    }                                                                        \
  }                                                                          \
  /* ---- arrive: my h stores are at the coherence point ---- */             \
  asm volatile("s_waitcnt vmcnt(0)" ::: "memory");                           \
  __syncthreads();                                                           \
  if (tid == 0)                                                              \
    __hip_atomic_fetch_add(ctrp, 1u, __ATOMIC_RELAXED,                       \
                           __HIP_MEMORY_SCOPE_AGENT);                        \
}

__global__ void __launch_bounds__(256, 1)
gru_persist(const float* __restrict__ m_enc,
            const float* __restrict__ w_ih,
            const float* __restrict__ w_hh,
            const float* __restrict__ b_ih,
            const float* __restrict__ b_hh,
            float* __restrict__ out,
            u32* __restrict__ ws)   // [2][BB][HH] packed h + barrier counters
{
  extern __shared__ u16 lds_w[];      // [192][WPITCH]; rows 0..95 hi, 96..191 lo

  const int tid  = threadIdx.x;
  const int wave = tid >> 6;
  const int lane = tid & 63;
  const int wg   = blockIdx.x;
  const int bi   = wg & 1;            // batch half  (= barrier group)
  const int hj   = wg >> 1;           // hidden slice 0..15
  const int col0 = hj * HS;

  // ---- stage weight slices into LDS as hi/lo bf16 (one-time) ----
  for (int r = wave; r < 96; r += 4) {
    const int m  = r / 48;            // 0 = w_ih, 1 = w_hh
    const int g  = (r % 48) / 16;     // gate 0=r,1=z,2=n
    const int rr = r % 16;
    const float* src = (m ? w_hh : w_ih) + (size_t)(g * HH + col0 + rr) * HH;
    u16* dhi = &lds_w[r * WPITCH];
    u16* dlo = &lds_w[LO_OFF + r * WPITCH];
    for (int c = lane; c < HH; c += 64) {
      const float f  = src[c];
      const u16 hi   = f2b(f);
      dhi[c] = hi;
      dlo[c] = f2b(f - b2f(hi));
    }
  }
  __syncthreads();

  // ---- per-lane constants ----
  const int arow = lane & 15;
  const int quad = lane >> 4;
  const int row0 = bi * BS + wave * 16;
  const int cd   = col0 + arow;

  const float bsum_r = b_ih[cd]          + b_hh[cd];
  const float bsum_z = b_ih[HH + cd]     + b_hh[HH + cd];
  const float bi_n   = b_ih[2 * HH + cd];
  const float bh_n   = b_hh[2 * HH + cd];

  const int abrow = row0 + arow;
  const float* xrowbase = m_enc + (size_t)abrow * TT * HH + quad * 8;

  u32* const hb0  = ws;
  u32* const ctrp = ws + CTR_OFF + (size_t)bi * 64;  // groups on separate lines

  int woff[2][3];
#pragma unroll
  for (int m = 0; m < 2; ++m)
#pragma unroll
    for (int g = 0; g < 3; ++g)
      woff[m][g] = (m * 48 + g * 16 + arow) * WPITCH + quad * 8;

  float hprev[4] = {0.f, 0.f, 0.f, 0.f};

  f32x4 xA[16], xB[16];
  XLOAD(xA, TT - 1);                   // prologue: x tile for step 0

  for (int s2 = 0; s2 < TT; s2 += 2) { // unroll-2: static x double-buffer
    GRU_STEP(s2,     xA, xB);
    GRU_STEP(s2 + 1, xB, xA);
  }
}

extern "C" void kernel_launch(void* const* d_in, const int* in_sizes, int n_in,
                              void* d_out, int out_size, void* d_ws, size_t ws_size,
                              hipStream_t stream) {
  const float* m_enc = (const float*)d_in[0];
  const float* w_ih  = (const float*)d_in[1];
  const float* w_hh  = (const float*)d_in[2];
  const float* b_ih  = (const float*)d_in[3];
  const float* b_hh  = (const float*)d_in[4];
  float* out = (float*)d_out;
  u32*   ws  = (u32*)d_ws;   // [2][128][256] packed h (256 KiB) + counters

  hipFuncSetAttribute((const void*)gru_persist,
                      hipFuncAttributeMaxDynamicSharedMemorySize, LDS_BYTES);

  // zero h double-buffer (h0 = 0) AND barrier counters each launch
  hipMemsetAsync(d_ws, 0, (2 * (size_t)BB * HH + 256) * sizeof(u32), stream);

  void* args[] = { (void*)&m_enc, (void*)&w_ih, (void*)&w_hh,
                   (void*)&b_ih, (void*)&b_hh, (void*)&out, (void*)&ws };
  hipLaunchCooperativeKernel((const void*)gru_persist, dim3(NWG), dim3(256),
                             args, LDS_BYTES, stream);
}

// Round 2
// 4160.210 us; speedup vs baseline: 3.4088x; 3.0533x over previous
//
#include <hip/hip_runtime.h>

// GRU (reverse scan), B=128 T=1024 H=256. fp32 in/out.
// Persistent cooperative kernel, 128 WGs = 8 batch-groups x 16 hidden slices,
// 128 threads/WG (wave0 = compute, wave1 = x-producer).
// Compensated bf16 MFMA (Whi*hi + Whi*lo + Wlo*hi), OPERAND-SWAPPED:
//   acc = mfma(W_frag, xh_frag)  ->  D rows = hidden cols, D cols = batch row.
// Per-lane epilogue therefore owns (1 batch row x 4 contiguous hidden cols):
//   h-store = 2 u64 agent atomics (16B contiguous), out = 1 nt f32x4.
// h exchange: 32 wave-uniform contiguous u64 agent loads -> LDS bounce
// (1040B pitch, conflict-free) -> b128 fragment reads.
// Weights in frag-linear LDS blocks (base + lane*16): zero bank conflicts.
// Sync: per-WG flag slots (relaxed agent stores after vmcnt(0)), 16-lane poll.

#define TT 1024
#define BB 128
#define HH 256

typedef unsigned short u16;
typedef unsigned int   u32;
typedef unsigned long long u64;
typedef __attribute__((ext_vector_type(8))) short  bf16x8;
typedef __attribute__((ext_vector_type(4))) float  f32x4;
typedef __attribute__((ext_vector_type(4))) u32    u32x4;

static constexpr int NWG_B = 8;     // batch groups (16 rows each)
static constexpr int NWG_H = 16;    // hidden slices (16 cols each)
static constexpr int NWG   = NWG_B * NWG_H;   // 128 workgroups
static constexpr int BSR   = 16;    // batch rows per WG

// ---- LDS map (bytes) ----
// weights: 96 blocks of 1KB, block = (((m*3+g)*8+kf)*2+plane), data at lane*16
static constexpr int W_OFF  = 0;
// xbuf: 2 bufs x 8 kf x 2 halves x 1KB, packed u32 (lo16<<16|hi16)
static constexpr int X_OFF  = 96 * 1024;            // 98304
// h bounce: 16 rows x 1040B pitch (odd multiple of 16B -> conflict-free b128)
static constexpr int HB_OFF = X_OFF + 32 * 1024;    // 131072
static constexpr int HB_PITCH = 1040;
static constexpr int LDS_BYTES = HB_OFF + BSR * HB_PITCH;  // 147712

static constexpr int FLAGS_OFF_U32 = 2 * BB * HH;   // u32 index in ws

__device__ __forceinline__ float b2f(u16 u) {
  union { unsigned i; float f; } v; v.i = ((unsigned)u) << 16; return v.f;
}
__device__ __forceinline__ u16 f2b(float f) {   // RNE fp32 -> bf16
  union { float f; unsigned i; } v; v.f = f;
  return (u16)((v.i + 0x7fffu + ((v.i >> 16) & 1u)) >> 16);
}
__device__ __forceinline__ float sigm(float x) { return 1.0f / (1.0f + __expf(-x)); }
__device__ __forceinline__ float tanh_fast(float x) {
  float a = fabsf(x);
  float e = __expf(-2.0f * a);
  float t = (1.0f - e) / (1.0f + e);
  return copysignf(t, x);
}
__device__ __forceinline__ void split8r(f32x4 a, f32x4 b, bf16x8& hi, bf16x8& lo) {
  union { bf16x8 v; u16 e[8]; } uh, ul;
#pragma unroll
  for (int j = 0; j < 4; ++j) {
    const u16 h0 = f2b(a[j]); uh.e[j]     = h0; ul.e[j]     = f2b(a[j] - b2f(h0));
    const u16 h1 = f2b(b[j]); uh.e[4 + j] = h1; ul.e[4 + j] = f2b(b[j] - b2f(h1));
  }
  hi = uh.v; lo = ul.v;
}
// unpack 8 packed (lo16<<16|hi16) words into hi/lo bf16 fragments
__device__ __forceinline__ void unpack8(const u32* w, bf16x8& hi, bf16x8& lo) {
  union { bf16x8 v; u32 u[4]; } fh, fl;
#pragma unroll
  for (int j = 0; j < 4; ++j) {
    const u32 a = w[2 * j], b = w[2 * j + 1];
    fh.u[j] = (a & 0xffffu) | (b << 16);          // hi halves
    fl.u[j] = (a >> 16) | (b & 0xffff0000u);      // lo halves
  }
  hi = fh.v; lo = fl.v;
}

#define MFMA __builtin_amdgcn_mfma_f32_16x16x32_bf16

__global__ void __launch_bounds__(128, 1)
gru_persist(const float* __restrict__ m_enc,
            const float* __restrict__ w_ih,
            const float* __restrict__ w_hh,
            const float* __restrict__ b_ih,
            const float* __restrict__ b_hh,
            float* __restrict__ out,
            u32* __restrict__ ws)
{
  extern __shared__ char lds[];

  const int tid  = threadIdx.x;
  const int wv   = tid >> 6;
  const int lane = tid & 63;
  const int wg   = blockIdx.x;
  const int grp  = wg & 7;            // batch group (rows grp*16..+15)
  const int sl   = wg >> 3;           // hidden slice 0..15
  const int col0 = sl * 16;
  const int arow = lane & 15;
  const int quad = lane >> 4;
  const int row0 = grp * BSR;
  const int b    = row0 + arow;       // wave0: this lane's batch row
  const int cd4  = col0 + quad * 4;   // wave0: this lane's first hidden col

  // ---- stage weight fragments into frag-linear LDS blocks (one-time) ----
  for (int p = wv; p < 48; p += 2) {
    const int m  = p / 24;            // 0 = w_ih, 1 = w_hh
    const int g  = (p / 8) % 3;       // gate 0=r,1=z,2=n
    const int kf = p % 8;
    const float* src = (m ? w_hh : w_ih)
                     + (size_t)(g * HH + col0 + arow) * HH + kf * 32 + quad * 8;
    f32x4 a = *(const f32x4*)src;
    f32x4 c = *(const f32x4*)(src + 4);
    bf16x8 hi, lo; split8r(a, c, hi, lo);
    char* base = lds + W_OFF + (size_t)(((m * 3 + g) * 8 + kf) * 2) * 1024;
    *(bf16x8*)(base + lane * 16)        = hi;
    *(bf16x8*)(base + 1024 + lane * 16) = lo;
  }

  // ---- x producer: split + pack one timestep into xbuf[buf] ----
  auto produce = [&](int buf, int tsv) {
    const float* xb = m_enc + (size_t)(row0 + arow) * TT * HH
                      + (size_t)tsv * HH + quad * 8;
#pragma unroll
    for (int kf = 0; kf < 8; ++kf) {
      f32x4 a = *(const f32x4*)(xb + kf * 32);
      f32x4 c = *(const f32x4*)(xb + kf * 32 + 4);
      bf16x8 hi, lo; split8r(a, c, hi, lo);
      union { bf16x8 v; u16 e[8]; } uh, ul; uh.v = hi; ul.v = lo;
      u32 p0[4], p1[4];
#pragma unroll
      for (int j = 0; j < 4; ++j) {
        p0[j] = (u32)uh.e[j]     | ((u32)ul.e[j]     << 16);
        p1[j] = (u32)uh.e[4 + j] | ((u32)ul.e[4 + j] << 16);
      }
      char* xd = lds + X_OFF + (size_t)((buf * 8 + kf) * 2) * 1024;
      *(u32x4*)(xd + lane * 16)        = *(u32x4*)p0;
      *(u32x4*)(xd + 1024 + lane * 16) = *(u32x4*)p1;
    }
  };

  // biases as f32x4 over this lane's 4 hidden cols
  const f32x4 br4  = *(const f32x4*)(b_ih + cd4) + *(const f32x4*)(b_hh + cd4);
  const f32x4 bz4  = *(const f32x4*)(b_ih + HH + cd4) + *(const f32x4*)(b_hh + HH + cd4);
  const f32x4 bin4 = *(const f32x4*)(b_ih + 2 * HH + cd4);
  const f32x4 bhn4 = *(const f32x4*)(b_hh + 2 * HH + cd4);

  u32* const hb0   = ws;
  u32* const flags = ws + FLAGS_OFF_U32;   // [8 groups][64 u32] (256B/group)

  if (wv == 1) produce(0, TT - 1);   // x for step 0
  __syncthreads();

  float hprev[4] = {0.f, 0.f, 0.f, 0.f};

  for (int s = 0; s < TT; ++s) {
    __syncthreads();   // B_s: xbuf[(s)&1] ready; xbuf[(s+1)&1] free for wave1

    if (wv == 0) {
      const int ts = TT - 1 - s;
      const int rb = s & 1;

      f32x4 air = {0,0,0,0}, aiz = {0,0,0,0}, ain = {0,0,0,0};
      f32x4 ahr = {0,0,0,0}, ahz = {0,0,0,0}, ahn = {0,0,0,0};

      // ---- x-side MFMAs (no h dependence; runs while producers finish) ----
#pragma unroll
      for (int kf = 0; kf < 8; ++kf) {
        char* xd = lds + X_OFF + (size_t)((rb * 8 + kf) * 2) * 1024;
        u32 xw[8];
        *(u32x4*)xw       = *(u32x4*)(xd + lane * 16);
        *(u32x4*)(xw + 4) = *(u32x4*)(xd + 1024 + lane * 16);
        bf16x8 xhi, xlo; unpack8(xw, xhi, xlo);
        char* wb = lds + W_OFF + (size_t)(kf * 2) * 1024 + lane * 16;  // m=0,g=0
        bf16x8 wr  = *(bf16x8*)(wb);
        bf16x8 wrl = *(bf16x8*)(wb + 1024);
        bf16x8 wz  = *(bf16x8*)(wb + 16384);        // g=1: +8 blocks
        bf16x8 wzl = *(bf16x8*)(wb + 16384 + 1024);
        bf16x8 wn  = *(bf16x8*)(wb + 32768);        // g=2: +16 blocks
        bf16x8 wnl = *(bf16x8*)(wb + 32768 + 1024);
        air = MFMA(wr, xhi, air, 0, 0, 0);
        aiz = MFMA(wz, xhi, aiz, 0, 0, 0);
        ain = MFMA(wn, xhi, ain, 0, 0, 0);
        air = MFMA(wr, xlo, air, 0, 0, 0);
        aiz = MFMA(wz, xlo, aiz, 0, 0, 0);
        ain = MFMA(wn, xlo, ain, 0, 0, 0);
        air = MFMA(wrl, xhi, air, 0, 0, 0);
        aiz = MFMA(wzl, xhi, aiz, 0, 0, 0);
        ain = MFMA(wnl, xhi, ain, 0, 0, 0);
      }

      // ---- wait: group mates finished step s-1 ----
      if (s > 0) {
        const u32* fp = &flags[grp * 64 + (lane & 15)];
        while (true) {
          u32 f = __hip_atomic_load(fp, __ATOMIC_RELAXED, __HIP_MEMORY_SCOPE_AGENT);
          if (__all((int)(f >= (u32)s))) break;
          __builtin_amdgcn_s_sleep(1);
        }
        asm volatile("" ::: "memory");   // compiler fence: keep loads below
      }

      // ---- h loads: 32 wave-uniform contiguous 512B chunks (u64/lane) ----
      u64 hr[32];
      const u64* hsrc = (const u64*)(hb0 + (size_t)rb * BB * HH + (size_t)row0 * HH);
#pragma unroll
      for (int i = 0; i < 32; ++i)   // i = row*2 + half
        hr[i] = __hip_atomic_load(hsrc + (size_t)(i >> 1) * 128 + (i & 1) * 64 + lane,
                                  __ATOMIC_RELAXED, __HIP_MEMORY_SCOPE_AGENT);
      // bounce into padded LDS (conflict-free writes and reads)
#pragma unroll
      for (int i = 0; i < 32; ++i)
        *(u64*)(lds + HB_OFF + (i >> 1) * HB_PITCH + (i & 1) * 512 + lane * 8) = hr[i];

      // ---- h-side MFMAs ----
#pragma unroll
      for (int kf = 0; kf < 8; ++kf) {
        u32 hw[8];
        char* hbp = lds + HB_OFF + arow * HB_PITCH + kf * 128 + quad * 32;
        *(u32x4*)hw       = *(u32x4*)hbp;
        *(u32x4*)(hw + 4) = *(u32x4*)(hbp + 16);
        bf16x8 hhi, hlo; unpack8(hw, hhi, hlo);
        char* wb = lds + W_OFF + 49152 + (size_t)(kf * 2) * 1024 + lane * 16;  // m=1
        bf16x8 vr  = *(bf16x8*)(wb);
        bf16x8 vrl = *(bf16x8*)(wb + 1024);
        bf16x8 vz  = *(bf16x8*)(wb + 16384);
        bf16x8 vzl = *(bf16x8*)(wb + 16384 + 1024);
        bf16x8 vn  = *(bf16x8*)(wb + 32768);
        bf16x8 vnl = *(bf16x8*)(wb + 32768 + 1024);
        ahr = MFMA(vr, hhi, ahr, 0, 0, 0);
        ahz = MFMA(vz, hhi, ahz, 0, 0, 0);
        ahn = MFMA(vn, hhi, ahn, 0, 0, 0);
        ahr = MFMA(vr, hlo, ahr, 0, 0, 0);
        ahz = MFMA(vz, hlo, ahz, 0, 0, 0);
        ahn = MFMA(vn, hlo, ahn, 0, 0, 0);
        ahr = MFMA(vrl, hhi, ahr, 0, 0, 0);
        ahz = MFMA(vzl, hhi, ahz, 0, 0, 0);
        ahn = MFMA(vnl, hhi, ahn, 0, 0, 0);
      }

      // ---- gates + state update (lane owns 1 batch row x 4 hidden cols) ----
      f32x4 hnew;
      u32 pk[4];
#pragma unroll
      for (int i = 0; i < 4; ++i) {
        const float rg = sigm(air[i] + ahr[i] + br4[i]);
        const float zg = sigm(aiz[i] + ahz[i] + bz4[i]);
        const float ng = tanh_fast(ain[i] + bin4[i] + rg * (ahn[i] + bhn4[i]));
        const float hv = (1.0f - zg) * ng + zg * hprev[i];
        hprev[i] = hv; hnew[i] = hv;
        const u16 ph = f2b(hv);
        pk[i] = (u32)ph | ((u32)f2b(hv - b2f(ph)) << 16);
      }
      u64* hdst = (u64*)(hb0 + (size_t)(rb ^ 1) * BB * HH + (size_t)b * HH + cd4);
      __hip_atomic_store(hdst,     (u64)pk[0] | ((u64)pk[1] << 32),
                         __ATOMIC_RELAXED, __HIP_MEMORY_SCOPE_AGENT);
      __hip_atomic_store(hdst + 1, (u64)pk[2] | ((u64)pk[3] << 32),
                         __ATOMIC_RELAXED, __HIP_MEMORY_SCOPE_AGENT);

      // ---- release: h at coherence point, then publish flag ----
      asm volatile("s_waitcnt vmcnt(0)" ::: "memory");
      if (lane == 0)
        __hip_atomic_store(&flags[grp * 64 + sl], (u32)(s + 1),
                           __ATOMIC_RELAXED, __HIP_MEMORY_SCOPE_AGENT);

      // out-store after flag publish: drain cost off the critical path
      __builtin_nontemporal_store(hnew,
          (f32x4*)(out + ((size_t)b * TT + ts) * HH + cd4));
    } else {
      if (s + 1 < TT) produce((s + 1) & 1, TT - 2 - s);
    }
  }
}

extern "C" void kernel_launch(void* const* d_in, const int* in_sizes, int n_in,
                              void* d_out, int out_size, void* d_ws, size_t ws_size,
                              hipStream_t stream) {
  const float* m_enc = (const float*)d_in[0];
  const float* w_ih  = (const float*)d_in[1];
  const float* w_hh  = (const float*)d_in[2];
  const float* b_ih  = (const float*)d_in[3];
  const float* b_hh  = (const float*)d_in[4];
  float* out = (float*)d_out;
  u32*   ws  = (u32*)d_ws;   // [2][128][256] packed h (256 KiB) + flags (2 KiB)

  hipFuncSetAttribute((const void*)gru_persist,
                      hipFuncAttributeMaxDynamicSharedMemorySize, LDS_BYTES);

  // zero h double-buffer (h0 = 0) AND flag slots each launch
  hipMemsetAsync(d_ws, 0, (size_t)(2 * BB * HH) * sizeof(u32) + 2048, stream);

  void* args[] = { (void*)&m_enc, (void*)&w_ih, (void*)&w_hh,
                   (void*)&b_ih, (void*)&b_hh, (void*)&out, (void*)&ws };
  hipLaunchCooperativeKernel((const void*)gru_persist, dim3(NWG), dim3(128),
                             args, LDS_BYTES, stream);
}